// Round 1
// baseline (3381.625 us; speedup 1.0000x reference)
//
#include <hip/hip_runtime.h>
#include <stdint.h>

#define BB 512
#define TT 64
#define OBSD 1024
#define ACTD 32
#define HD 1024
#define SD 64
#define BT (BB*TT)
#define G3 (3*HD)

typedef unsigned short u16;
typedef __attribute__((ext_vector_type(8))) short bf16x8;
typedef __attribute__((ext_vector_type(4))) float f32x4;

__device__ __forceinline__ float bf2f(u16 v){ uint32_t u = ((uint32_t)v)<<16; return __builtin_bit_cast(float,u); }
__device__ __forceinline__ u16 f2bf(float f){ uint32_t u = __builtin_bit_cast(uint32_t,f); uint32_t r = (u + 0x7FFFu + ((u>>16)&1u))>>16; return (u16)r; }

// ---------- f32 -> bf16 convert (RNE) ----------
__global__ void cvt_kernel(const float* __restrict__ in, u16* __restrict__ out, long n){
  long i = (long)blockIdx.x*blockDim.x + threadIdx.x;
  long st = (long)gridDim.x*blockDim.x;
  for (; i<n; i+=st) out[i] = f2bf(in[i]);
}

// ---------- generic bf16 MFMA GEMM: C[M,N] = A[M,K] * W[N,K]^T (+bias) ----------
// A and B each described by up to 3 K-segments (boundaries multiple of 32).
struct GemmP {
  const u16* a0; const u16* a1; const u16* a2;
  const u16* b0; const u16* b1; const u16* b2;
  long lda0, lda1, lda2, ldb0, ldb1, ldb2;
  int kc0, kc1, kc2, kcPerZ;      // cumulative K-chunk (32) ends; chunks per z-slice
  float* cf; u16* cb;
  long ldc, ldcb, zstride;
  const float* bias0; const float* bias1;
  int relu;
};

template<int BM,int BN>
__global__ __launch_bounds__(256) void gemm_bf16(GemmP p){
  constexpr int SA = 40;                 // 32 + 8 pad halves: 2-way LDS aliasing only
  __shared__ u16 sA[BM*SA];
  __shared__ u16 sB[BN*SA];
  const int m0 = blockIdx.y*BM, n0 = blockIdx.x*BN;
  const int tid = threadIdx.x, lane = tid&63, wave = tid>>6;
  const int wm = (wave>>1)*(BM/2), wn = (wave&1)*(BN/2);
  constexpr int FM = BM/32, FN = BN/32;
  f32x4 acc[FM][FN] = {};
  const int cbeg = blockIdx.z*p.kcPerZ;
  int cend = cbeg + p.kcPerZ; if (cend > p.kc2) cend = p.kc2;
  const int sr = tid>>2, sc = (tid&3)*8;
  const int kg = lane>>4, lr = lane&15;
  for (int c=cbeg;c<cend;++c){
    const u16* ap; const u16* bp; long lda, ldb; int kofs;
    if (c < p.kc0){ ap=p.a0; bp=p.b0; lda=p.lda0; ldb=p.ldb0; kofs=c*32; }
    else if (c < p.kc1){ ap=p.a1; bp=p.b1; lda=p.lda1; ldb=p.ldb1; kofs=(c-p.kc0)*32; }
    else { ap=p.a2; bp=p.b2; lda=p.lda2; ldb=p.ldb2; kofs=(c-p.kc1)*32; }
    #pragma unroll
    for (int it=0; it<BM/64; ++it){
      int row = sr + it*64;
      *(bf16x8*)&sA[row*SA+sc] = *(const bf16x8*)(ap + (long)(m0+row)*lda + kofs + sc);
    }
    #pragma unroll
    for (int it=0; it<BN/64; ++it){
      int row = sr + it*64;
      *(bf16x8*)&sB[row*SA+sc] = *(const bf16x8*)(bp + (long)(n0+row)*ldb + kofs + sc);
    }
    __syncthreads();
    bf16x8 af[FM], bfv[FN];
    #pragma unroll
    for (int i=0;i<FM;++i) af[i] = *(const bf16x8*)&sA[(wm+i*16+lr)*SA + kg*8];
    #pragma unroll
    for (int j=0;j<FN;++j) bfv[j] = *(const bf16x8*)&sB[(wn+j*16+lr)*SA + kg*8];
    #pragma unroll
    for (int i=0;i<FM;++i)
      #pragma unroll
      for (int j=0;j<FN;++j)
        acc[i][j] = __builtin_amdgcn_mfma_f32_16x16x32_bf16(af[i], bfv[j], acc[i][j], 0,0,0);
    __syncthreads();
  }
  const bool partial = (gridDim.z > 1);
  float* cf = p.cf ? (p.cf + (partial ? (long)blockIdx.z*p.zstride : 0)) : nullptr;
  #pragma unroll
  for (int i=0;i<FM;++i){
    #pragma unroll
    for (int j=0;j<FN;++j){
      const int gr0 = m0 + wm + i*16 + kg*4;
      const int gc = n0 + wn + j*16 + lr;
      float bias = 0.f;
      if (!partial){
        if (p.bias0) bias += p.bias0[gc];
        if (p.bias1) bias += p.bias1[gc];
      }
      #pragma unroll
      for (int r=0;r<4;++r){
        float v = acc[i][j][r] + bias;
        if (p.relu) v = fmaxf(v, 0.f);
        const long row = gr0 + r;
        if (cf) cf[row*p.ldc + gc] = v;
        if (p.cb) p.cb[row*p.ldcb + gc] = f2bf(v);
      }
    }
  }
}

// ---------- GRU gate epilogue: torch GRUCell ----------
__global__ void gru_gate_ep(const float* __restrict__ gh, const float* __restrict__ gi,
                            const float* __restrict__ b_ih, const float* __restrict__ b_hh,
                            float* __restrict__ deterF, u16* __restrict__ det_bf_t){
  int idx = blockIdx.x*256 + threadIdx.x;   // BB*HD
  int b = idx >> 10, h = idx & 1023;
  const float* ghr = gh + (long)b*G3;
  const float* gir = gi + (long)b*G3;
  float rp  = ghr[h]      + gir[h]      + b_ih[h]      + b_hh[h];
  float zp  = ghr[h+HD]   + gir[h+HD]   + b_ih[h+HD]   + b_hh[h+HD];
  float hn  = ghr[h+2*HD] + b_hh[h+2*HD];
  float inn = gir[h+2*HD] + b_ih[h+2*HD];
  float r = 1.f/(1.f+expf(-rp));
  float z = 1.f/(1.f+expf(-zp));
  float n = tanhf(inn + r*hn);
  float d = (1.f - z)*n + z*deterF[idx];
  deterF[idx] = d;
  det_bf_t[(long)b*(TT*HD) + h] = f2bf(d);
}

// ---------- posterior epilogue: sum split-K partials, softplus, reparam ----------
__global__ void post_ep(const float* __restrict__ parts, const float* __restrict__ b_post,
                        const float* __restrict__ eps_t, float* __restrict__ qm_t,
                        float* __restrict__ qs_t, u16* __restrict__ sto_t){
  int idx = blockIdx.x*256 + threadIdx.x;   // BB*SD
  int b = idx>>6, s = idx&63;
  float m = b_post[s], rs = b_post[s+SD];
  #pragma unroll
  for (int z=0; z<8; ++z){
    const float* pz = parts + (long)z*(BB*2*SD) + (long)b*(2*SD);
    m += pz[s]; rs += pz[s+SD];
  }
  float sp = fmaxf(rs,0.f) + log1pf(expf(-fabsf(rs)));
  float qs = sp + 1e-4f;
  float e = eps_t[(long)b*(TT*SD) + s];
  float st = m + e*qs;
  qm_t[(long)b*(TT*SD)+s] = m;
  qs_t[(long)b*(TT*SD)+s] = qs;
  sto_t[(long)b*(TT*SD)+s] = f2bf(st);
}

// ---------- KL per row (wave per row, lane = s) ----------
__global__ void kl_kernel(const float* __restrict__ pbuf, const float* __restrict__ qm,
                          const float* __restrict__ qs, float* __restrict__ klrows){
  int m = blockIdx.x*4 + (threadIdx.x>>6);
  int s = threadIdx.x & 63;
  float pm   = pbuf[(long)m*128 + s];
  float praw = pbuf[(long)m*128 + 64 + s];
  float ps = fmaxf(praw,0.f) + log1pf(expf(-fabsf(praw))) + 1e-4f;
  float qmv = qm[(long)m*64+s], qsv = qs[(long)m*64+s];
  float d = qmv - pm;
  float kl = logf(ps/qsv) + (qsv*qsv + d*d)/(2.f*ps*ps) - 0.5f;
  #pragma unroll
  for (int off=32; off; off>>=1) kl += __shfl_xor(kl, off);
  if (s==0) klrows[m] = kl*(1.f/64.f);
}

__global__ void kl_reduce(const float* __restrict__ klrows, float* __restrict__ out){
  __shared__ float sm[256];
  float a = 0.f;
  for (int i=threadIdx.x; i<BT; i+=256) a += klrows[i];
  sm[threadIdx.x]=a; __syncthreads();
  for (int off=128; off; off>>=1){ if ((int)threadIdx.x<off) sm[threadIdx.x]+=sm[threadIdx.x+off]; __syncthreads(); }
  if (threadIdx.x==0) out[0] = sm[0] / (float)BT;
}

// ---------- reward/done heads (wave per row) ----------
__global__ void rewdone_kernel(const u16* __restrict__ det, const u16* __restrict__ sto,
    const float* __restrict__ Wr, const float* __restrict__ br,
    const float* __restrict__ Wd, const float* __restrict__ bd,
    float* __restrict__ orew, float* __restrict__ odone){
  int m = blockIdx.x*4 + (threadIdx.x>>6);
  int lane = threadIdx.x & 63;
  float ar=0.f, ad=0.f;
  for (int k=lane; k<HD+SD; k+=64){
    float f = (k<HD) ? bf2f(det[(long)m*HD+k]) : bf2f(sto[(long)m*SD + (k-HD)]);
    ar = fmaf(f, Wr[k], ar); ad = fmaf(f, Wd[k], ad);
  }
  #pragma unroll
  for (int off=32; off; off>>=1){ ar += __shfl_xor(ar, off); ad += __shfl_xor(ad, off); }
  if (lane==0){ orew[m]=ar+br[0]; odone[m]=ad+bd[0]; }
}

static char* carve(char*& base, size_t bytes){
  char* p = base; base += (bytes + 255) & ~(size_t)255; return p;
}

extern "C" void kernel_launch(void* const* d_in, const int* in_sizes, int n_in,
                              void* d_out, int out_size, void* d_ws, size_t ws_size,
                              hipStream_t stream) {
  const float* obs    = (const float*)d_in[0];
  const float* action = (const float*)d_in[1];
  const float* eps    = (const float*)d_in[2];
  const float* W_enc  = (const float*)d_in[3];
  const float* b_enc  = (const float*)d_in[4];
  const float* W_ih   = (const float*)d_in[5];
  const float* W_hh   = (const float*)d_in[6];
  const float* b_ih   = (const float*)d_in[7];
  const float* b_hh   = (const float*)d_in[8];
  const float* W_prior= (const float*)d_in[9];
  const float* b_prior= (const float*)d_in[10];
  const float* W_post = (const float*)d_in[11];
  const float* b_post = (const float*)d_in[12];
  const float* W_dec1 = (const float*)d_in[13];
  const float* b_dec1 = (const float*)d_in[14];
  const float* W_dec2 = (const float*)d_in[15];
  const float* b_dec2 = (const float*)d_in[16];
  const float* W_rew  = (const float*)d_in[17];
  const float* b_rew  = (const float*)d_in[18];
  const float* W_done = (const float*)d_in[19];
  const float* b_done = (const float*)d_in[20];

  char* w = (char*)d_ws;
  u16* obs_bf  = (u16*)carve(w, (size_t)BT*OBSD*2);   // later reused as hid_bf
  u16* emb_bf  = (u16*)carve(w, (size_t)BT*HD*2);
  u16* det_bf  = (u16*)carve(w, (size_t)BT*HD*2);
  u16* sto_bf  = (u16*)carve(w, (size_t)BT*SD*2);
  u16* act_bf  = (u16*)carve(w, (size_t)BT*ACTD*2);
  u16* Wenc_bf = (u16*)carve(w, (size_t)HD*OBSD*2);
  u16* Wih_bf  = (u16*)carve(w, (size_t)G3*(SD+ACTD)*2);
  u16* Whh_bf  = (u16*)carve(w, (size_t)G3*HD*2);
  u16* Wpri_bf = (u16*)carve(w, (size_t)2*SD*HD*2);
  u16* Wpos_bf = (u16*)carve(w, (size_t)2*SD*2*HD*2);
  u16* Wd1_bf  = (u16*)carve(w, (size_t)HD*(HD+SD)*2);
  u16* Wd2_bf  = (u16*)carve(w, (size_t)OBSD*HD*2);
  u16* zero_bf = (u16*)carve(w, 4096);
  float* deterF = (float*)carve(w, (size_t)BB*HD*4);
  float* g_h    = (float*)carve(w, (size_t)BB*G3*4);
  float* g_i    = (float*)carve(w, (size_t)BB*G3*4);
  float* qparts = (float*)carve(w, (size_t)8*BB*2*SD*4);
  float* qm_all = (float*)carve(w, (size_t)BT*SD*4);
  float* qs_all = (float*)carve(w, (size_t)BT*SD*4);
  float* p_buf  = (float*)carve(w, (size_t)BT*2*SD*4);
  float* klrows = (float*)carve(w, (size_t)BT*4);
  u16* hid_bf = obs_bf;   // union: obs_bf dead after encoder

  if ((size_t)(w - (char*)d_ws) > ws_size){
    hipMemsetAsync(d_out, 0xFF, 4, stream);   // sentinel: NaN in out[0]
    return;
  }

  auto cvt = [&](const float* in, u16* out, long n){
    cvt_kernel<<<dim3(2048), dim3(256), 0, stream>>>(in, out, n);
  };
  cvt(obs, obs_bf, (long)BT*OBSD);
  cvt(action, act_bf, (long)BT*ACTD);
  cvt(W_enc, Wenc_bf, (long)HD*OBSD);
  cvt(W_ih, Wih_bf, (long)G3*(SD+ACTD));
  cvt(W_hh, Whh_bf, (long)G3*HD);
  cvt(W_prior, Wpri_bf, (long)2*SD*HD);
  cvt(W_post, Wpos_bf, (long)2*SD*2*HD);
  cvt(W_dec1, Wd1_bf, (long)HD*(HD+SD));
  cvt(W_dec2, Wd2_bf, (long)OBSD*HD);
  hipMemsetAsync(zero_bf, 0, 4096, stream);
  hipMemsetAsync(deterF, 0, (size_t)BB*HD*4, stream);

  // ---- Phase 1: encoder  emb = relu(obs @ W_enc^T + b_enc)  [bf16 out]
  {
    GemmP q{};
    q.a0 = obs_bf;  q.lda0 = OBSD;
    q.b0 = Wenc_bf; q.ldb0 = OBSD;
    q.kc0=q.kc1=q.kc2=32; q.kcPerZ=32;
    q.cb = emb_bf; q.ldcb = HD;
    q.bias0 = b_enc; q.relu = 1;
    gemm_bf16<128,128><<<dim3(HD/128, BT/128, 1), 256, 0, stream>>>(q);
  }

  // ---- Phase 2: sequential scan ----
  for (int t=0; t<TT; ++t){
    { // gh = deter_{t-1} @ W_hh^T
      GemmP q{};
      q.a0 = (t==0) ? zero_bf : (det_bf + (long)(t-1)*HD);
      q.lda0 = (t==0) ? 0 : (long)TT*HD;
      q.b0 = Whh_bf; q.ldb0 = HD;
      q.kc0=q.kc1=q.kc2=32; q.kcPerZ=32;
      q.cf = g_h; q.ldc = G3;
      gemm_bf16<64,128><<<dim3(G3/128, BB/64, 1), 256, 0, stream>>>(q);
    }
    { // gi = [stoch_{t-1}, a_t] @ W_ih^T
      GemmP q{};
      q.a0 = (t==0) ? zero_bf : (sto_bf + (long)(t-1)*SD);
      q.lda0 = (t==0) ? 0 : (long)TT*SD;
      q.a1 = act_bf + (long)t*ACTD; q.lda1 = (long)TT*ACTD;
      q.b0 = Wih_bf;      q.ldb0 = SD+ACTD;
      q.b1 = Wih_bf + SD; q.ldb1 = SD+ACTD;
      q.kc0=2; q.kc1=3; q.kc2=3; q.kcPerZ=3;
      q.cf = g_i; q.ldc = G3;
      gemm_bf16<64,128><<<dim3(G3/128, BB/64, 1), 256, 0, stream>>>(q);
    }
    gru_gate_ep<<<dim3(BB*HD/256), 256, 0, stream>>>(g_h, g_i, b_ih, b_hh,
                                                     deterF, det_bf + (long)t*HD);
    { // posterior GEMM, split-K = 8
      GemmP q{};
      q.a0 = det_bf + (long)t*HD; q.lda0 = (long)TT*HD;
      q.a1 = emb_bf + (long)t*HD; q.lda1 = (long)TT*HD;
      q.b0 = Wpos_bf;      q.ldb0 = 2*HD;
      q.b1 = Wpos_bf + HD; q.ldb1 = 2*HD;
      q.kc0=32; q.kc1=64; q.kc2=64; q.kcPerZ=8;
      q.cf = qparts; q.ldc = 2*SD; q.zstride = (long)BB*2*SD;
      gemm_bf16<64,64><<<dim3(2*SD/64, BB/64, 8), 256, 0, stream>>>(q);
    }
    post_ep<<<dim3(BB*SD/256), 256, 0, stream>>>(qparts, b_post,
        eps + (long)t*SD, qm_all + (long)t*SD, qs_all + (long)t*SD, sto_bf + (long)t*SD);
  }

  // ---- Phase 3: batched heads ----
  { // prior over all rows
    GemmP q{};
    q.a0 = det_bf;  q.lda0 = HD;
    q.b0 = Wpri_bf; q.ldb0 = HD;
    q.kc0=q.kc1=q.kc2=32; q.kcPerZ=32;
    q.cf = p_buf; q.ldc = 2*SD;
    q.bias0 = b_prior;
    gemm_bf16<64,64><<<dim3(2*SD/64, BT/64, 1), 256, 0, stream>>>(q);
  }
  kl_kernel<<<dim3(BT/4), 256, 0, stream>>>(p_buf, qm_all, qs_all, klrows);
  { // dec1: hid = relu(feat @ W_dec1^T + b_dec1)   [bf16 out, reuses obs_bf region]
    GemmP q{};
    q.a0 = det_bf; q.lda0 = HD;
    q.a1 = sto_bf; q.lda1 = SD;
    q.b0 = Wd1_bf;      q.ldb0 = HD+SD;
    q.b1 = Wd1_bf + HD; q.ldb1 = HD+SD;
    q.kc0=32; q.kc1=34; q.kc2=34; q.kcPerZ=34;
    q.cb = hid_bf; q.ldcb = HD;
    q.bias0 = b_dec1; q.relu = 1;
    gemm_bf16<128,128><<<dim3(HD/128, BT/128, 1), 256, 0, stream>>>(q);
  }
  { // dec2: pred = hid @ W_dec2^T + b_dec2 -> d_out (f32)
    GemmP q{};
    q.a0 = hid_bf; q.lda0 = HD;
    q.b0 = Wd2_bf; q.ldb0 = HD;
    q.kc0=q.kc1=q.kc2=32; q.kcPerZ=32;
    q.cf = (float*)d_out; q.ldc = OBSD;
    q.bias0 = b_dec2;
    gemm_bf16<128,128><<<dim3(OBSD/128, BT/128, 1), 256, 0, stream>>>(q);
  }
  rewdone_kernel<<<dim3(BT/4), 256, 0, stream>>>(det_bf, sto_bf, W_rew, b_rew, W_done, b_done,
      (float*)d_out + (long)BT*OBSD, (float*)d_out + (long)BT*OBSD + BT);
  kl_reduce<<<dim3(1), 256, 0, stream>>>(klrows, (float*)d_out + (long)BT*OBSD + 2*BT);
}

// Round 2
// 2280.937 us; speedup vs baseline: 1.4826x; 1.4826x over previous
//
#include <hip/hip_runtime.h>
#include <stdint.h>

#define BB 512
#define TT 64
#define OBSD 1024
#define ACTD 32
#define HD 1024
#define SD 64
#define BT (BB*TT)
#define G3 (3*HD)

typedef unsigned short u16;
typedef __attribute__((ext_vector_type(8))) short bf16x8;
typedef __attribute__((ext_vector_type(4))) float f32x4;

__device__ __forceinline__ float bf2f(u16 v){ uint32_t u = ((uint32_t)v)<<16; return __builtin_bit_cast(float,u); }
__device__ __forceinline__ u16 f2bf(float f){ uint32_t u = __builtin_bit_cast(uint32_t,f); uint32_t r = (u + 0x7FFFu + ((u>>16)&1u))>>16; return (u16)r; }
__device__ __forceinline__ float sigm(float x){ return 1.f/(1.f+expf(-x)); }

// ---------- f32 -> bf16 convert (RNE) ----------
__global__ void cvt_kernel(const float* __restrict__ in, u16* __restrict__ out, long n){
  long i = (long)blockIdx.x*blockDim.x + threadIdx.x;
  long st = (long)gridDim.x*blockDim.x;
  for (; i<n; i+=st) out[i] = f2bf(in[i]);
}

// ---------- generic bf16 MFMA GEMM: C[M,N] = A[M,K] * W[N,K]^T (+bias) ----------
struct GemmP {
  const u16* a0; const u16* a1; const u16* a2;
  const u16* b0; const u16* b1; const u16* b2;
  long lda0, lda1, lda2, ldb0, ldb1, ldb2;
  int kc0, kc1, kc2, kcPerZ;
  float* cf; u16* cb;
  long ldc, ldcb, zstride;
  const float* bias0; const float* bias1;
  int relu;
};

template<int BM,int BN>
__global__ __launch_bounds__(256) void gemm_bf16(GemmP p){
  constexpr int SA = 40;
  __shared__ u16 sA[BM*SA];
  __shared__ u16 sB[BN*SA];
  const int m0 = blockIdx.y*BM, n0 = blockIdx.x*BN;
  const int tid = threadIdx.x, lane = tid&63, wave = tid>>6;
  const int wm = (wave>>1)*(BM/2), wn = (wave&1)*(BN/2);
  constexpr int FM = BM/32, FN = BN/32;
  f32x4 acc[FM][FN] = {};
  const int cbeg = blockIdx.z*p.kcPerZ;
  int cend = cbeg + p.kcPerZ; if (cend > p.kc2) cend = p.kc2;
  const int sr = tid>>2, sc = (tid&3)*8;
  const int kg = lane>>4, lr = lane&15;
  for (int c=cbeg;c<cend;++c){
    const u16* ap; const u16* bp; long lda, ldb; int kofs;
    if (c < p.kc0){ ap=p.a0; bp=p.b0; lda=p.lda0; ldb=p.ldb0; kofs=c*32; }
    else if (c < p.kc1){ ap=p.a1; bp=p.b1; lda=p.lda1; ldb=p.ldb1; kofs=(c-p.kc0)*32; }
    else { ap=p.a2; bp=p.b2; lda=p.lda2; ldb=p.ldb2; kofs=(c-p.kc1)*32; }
    #pragma unroll
    for (int it=0; it<BM/64; ++it){
      int row = sr + it*64;
      *(bf16x8*)&sA[row*SA+sc] = *(const bf16x8*)(ap + (long)(m0+row)*lda + kofs + sc);
    }
    #pragma unroll
    for (int it=0; it<BN/64; ++it){
      int row = sr + it*64;
      *(bf16x8*)&sB[row*SA+sc] = *(const bf16x8*)(bp + (long)(n0+row)*ldb + kofs + sc);
    }
    __syncthreads();
    bf16x8 af[FM], bfv[FN];
    #pragma unroll
    for (int i=0;i<FM;++i) af[i] = *(const bf16x8*)&sA[(wm+i*16+lr)*SA + kg*8];
    #pragma unroll
    for (int j=0;j<FN;++j) bfv[j] = *(const bf16x8*)&sB[(wn+j*16+lr)*SA + kg*8];
    #pragma unroll
    for (int i=0;i<FM;++i)
      #pragma unroll
      for (int j=0;j<FN;++j)
        acc[i][j] = __builtin_amdgcn_mfma_f32_16x16x32_bf16(af[i], bfv[j], acc[i][j], 0,0,0);
    __syncthreads();
  }
  const bool partial = (gridDim.z > 1);
  float* cf = p.cf ? (p.cf + (partial ? (long)blockIdx.z*p.zstride : 0)) : nullptr;
  #pragma unroll
  for (int i=0;i<FM;++i){
    #pragma unroll
    for (int j=0;j<FN;++j){
      const int gr0 = m0 + wm + i*16 + kg*4;
      const int gc = n0 + wn + j*16 + lr;
      float bias = 0.f;
      if (!partial){
        if (p.bias0) bias += p.bias0[gc];
        if (p.bias1) bias += p.bias1[gc];
      }
      #pragma unroll
      for (int r=0;r<4;++r){
        float v = acc[i][j][r] + bias;
        if (p.relu) v = fmaxf(v, 0.f);
        const long row = gr0 + r;
        if (cf) cf[row*p.ldc + gc] = v;
        if (p.cb) p.cb[row*p.ldcb + gc] = f2bf(v);
      }
    }
  }
}

// ---------- fused GRU step: gates GEMM (x-part + deter-part) + GRUCell epilogue ----------
// Block: BM=32 batch rows x 32 h-cols x 3 gates. 35 K-chunks: 0..31 deter, 32..33 stoch, 34 act.
__global__ __launch_bounds__(256) void gru_step(
    const u16* __restrict__ sto_prev, long ssto,
    const u16* __restrict__ act_t,
    const u16* __restrict__ det_prev, long sdet,
    const u16* __restrict__ Wih, const u16* __restrict__ Whh,
    const float* __restrict__ b_ih, const float* __restrict__ b_hh,
    float* __restrict__ deterF, u16* __restrict__ det_out){
  constexpr int SA = 40;
  __shared__ u16 sA[32*SA];
  __shared__ u16 sB[96*SA];
  const int id = blockIdx.x;
  const int n = (id&7) + ((id>>7)<<3);     // XCD-grouped: same id%8 shares h-range
  const int m = (id>>3)&15;
  const int m0 = m*32, h0 = n*32;
  const int tid = threadIdx.x, lane = tid&63, wave = tid>>6;
  const int wm = wave>>1, wn = wave&1;
  const int lr = lane&15, kg = lane>>4;

  f32x4 aR = {}, aZ = {}, aNd = {}, aNx = {};

  auto aAddr = [&](int c, int row, int sc)->const u16*{
    if (c < 32) return det_prev + (long)(m0+row)*sdet + c*32 + sc;
    if (c < 34) return sto_prev + (long)(m0+row)*ssto + (c-32)*32 + sc;
    return act_t + (long)(m0+row)*((long)TT*ACTD) + sc;
  };
  auto bAddr = [&](int c, int l)->const u16*{
    int row = l>>2, sc = (l&3)*8;
    int g = row>>5, hr = row&31;
    if (c < 32) return Whh + (long)(g*1024 + h0 + hr)*HD + c*32 + sc;
    return Wih + (long)(g*1024 + h0 + hr)*(SD+ACTD) + (c-32)*32 + sc;
  };

  bf16x8 rA, rB0, rB1;
  auto loadc = [&](int c){
    rB0 = *(const bf16x8*)bAddr(c, tid);
    if (tid < 128){
      rA  = *(const bf16x8*)aAddr(c, tid>>2, (tid&3)*8);
      rB1 = *(const bf16x8*)bAddr(c, 256+tid);
    }
  };

  loadc(0);
  for (int c=0; c<35; ++c){
    *(bf16x8*)&sB[(tid>>2)*SA + (tid&3)*8] = rB0;
    if (tid < 128){
      *(bf16x8*)&sA[(tid>>2)*SA + (tid&3)*8] = rA;
      int l = 256+tid;
      *(bf16x8*)&sB[(l>>2)*SA + (l&3)*8] = rB1;
    }
    if (c < 34) loadc(c+1);
    __syncthreads();
    bf16x8 af = *(const bf16x8*)&sA[(wm*16+lr)*SA + kg*8];
    bf16x8 b0 = *(const bf16x8*)&sB[(     wn*16+lr)*SA + kg*8];
    bf16x8 b1 = *(const bf16x8*)&sB[(32 + wn*16+lr)*SA + kg*8];
    bf16x8 b2 = *(const bf16x8*)&sB[(64 + wn*16+lr)*SA + kg*8];
    aR = __builtin_amdgcn_mfma_f32_16x16x32_bf16(af, b0, aR, 0,0,0);
    aZ = __builtin_amdgcn_mfma_f32_16x16x32_bf16(af, b1, aZ, 0,0,0);
    if (c < 32) aNd = __builtin_amdgcn_mfma_f32_16x16x32_bf16(af, b2, aNd, 0,0,0);
    else        aNx = __builtin_amdgcn_mfma_f32_16x16x32_bf16(af, b2, aNx, 0,0,0);
    __syncthreads();
  }

  const int col = h0 + wn*16 + lr;
  const float bir = b_ih[col],      bhr = b_hh[col];
  const float biz = b_ih[col+HD],   bhz = b_hh[col+HD];
  const float bin = b_ih[col+2*HD], bhn = b_hh[col+2*HD];
  #pragma unroll
  for (int reg=0; reg<4; ++reg){
    const int row = m0 + wm*16 + kg*4 + reg;
    float r = sigm(aR[reg] + bir + bhr);
    float z = sigm(aZ[reg] + biz + bhz);
    float nn = tanhf(aNx[reg] + bin + r*(aNd[reg] + bhn));
    const long fidx = (long)row*HD + col;
    float d = (1.f - z)*nn + z*deterF[fidx];
    deterF[fidx] = d;
    det_out[(long)row*((long)TT*HD) + col] = f2bf(d);
  }
}

// ---------- fused posterior step: deter-half GEMM (wave-split K) + Qemb + softplus + reparam ----------
// Grid: 32 wgs, each 16 batch rows x 128 outputs, K=1024 (32 chunks, 8 per wave).
__global__ __launch_bounds__(256) void post_step(
    const u16* __restrict__ det_t,     // stride TT*HD
    const u16* __restrict__ Wpos,      // [128][2048], deter half = cols 0..1024
    const float* __restrict__ qemb_t,  // + b*(TT*128), already has b_post + emb part
    const float* __restrict__ eps_t,   // + b*(TT*SD)
    float* __restrict__ qm_t, float* __restrict__ qs_t, u16* __restrict__ sto_out){
  constexpr int SA = 40;
  __shared__ u16 sA4[4*16*SA];
  __shared__ u16 sB4[4*128*SA];
  const int m0 = blockIdx.x*16;
  const int tid = threadIdx.x, lane = tid&63, w = tid>>6;
  const int lr = lane&15, kg = lane>>4;

  f32x4 acc[8] = {};
  bf16x8 rA, rB[8];
  auto loadIter = [&](int i){
    #pragma unroll
    for (int rnd=0; rnd<8; ++rnd){
      int l = rnd*256 + tid;
      int q = l>>9, row = (l>>2)&127, sc = (l&3)*8;
      rB[rnd] = *(const bf16x8*)(Wpos + (long)row*(2*HD) + (q*8+i)*32 + sc);
    }
    { int q = tid>>6, row = (tid>>2)&15, sc = (tid&3)*8;
      rA = *(const bf16x8*)(det_t + (long)(m0+row)*((long)TT*HD) + (q*8+i)*32 + sc); }
  };

  loadIter(0);
  for (int i=0; i<8; ++i){
    #pragma unroll
    for (int rnd=0; rnd<8; ++rnd){
      int l = rnd*256 + tid;
      int q = l>>9, row = (l>>2)&127, sc = (l&3)*8;
      *(bf16x8*)&sB4[q*128*SA + row*SA + sc] = rB[rnd];
    }
    { int q = tid>>6, row = (tid>>2)&15, sc = (tid&3)*8;
      *(bf16x8*)&sA4[q*16*SA + row*SA + sc] = rA; }
    if (i < 7) loadIter(i+1);
    __syncthreads();
    bf16x8 af = *(const bf16x8*)&sA4[w*16*SA + lr*SA + kg*8];
    #pragma unroll
    for (int j=0; j<8; ++j){
      bf16x8 bf = *(const bf16x8*)&sB4[w*128*SA + (j*16+lr)*SA + kg*8];
      acc[j] = __builtin_amdgcn_mfma_f32_16x16x32_bf16(af, bf, acc[j], 0,0,0);
    }
    __syncthreads();
  }

  float* pf = (float*)sB4;   // 4*16*128 f32 = 32 KB, fits in sB4's 40 KB
  #pragma unroll
  for (int j=0; j<8; ++j)
    #pragma unroll
    for (int reg=0; reg<4; ++reg)
      pf[w*2048 + (kg*4+reg)*128 + j*16+lr] = acc[j][reg];
  __syncthreads();

  #pragma unroll
  for (int i=0; i<4; ++i){
    int p = tid + i*256;       // 16 rows x 64 s
    int row = p>>6, s = p&63;
    int b = m0 + row;
    float mval = pf[row*128+s]      + pf[2048+row*128+s]      + pf[4096+row*128+s]      + pf[6144+row*128+s];
    float rsv  = pf[row*128+64+s]   + pf[2048+row*128+64+s]   + pf[4096+row*128+64+s]   + pf[6144+row*128+64+s];
    mval += qemb_t[(long)b*((long)TT*128) + s];
    rsv  += qemb_t[(long)b*((long)TT*128) + 64 + s];
    float sp = fmaxf(rsv,0.f) + log1pf(expf(-fabsf(rsv)));
    float qsv = sp + 1e-4f;
    float e = eps_t[(long)b*((long)TT*SD) + s];
    float st = mval + e*qsv;
    qm_t[(long)b*((long)TT*SD) + s] = mval;
    qs_t[(long)b*((long)TT*SD) + s] = qsv;
    sto_out[(long)b*((long)TT*SD) + s] = f2bf(st);
  }
}

// ---------- KL per row (wave per row, lane = s) ----------
__global__ void kl_kernel(const float* __restrict__ pbuf, const float* __restrict__ qm,
                          const float* __restrict__ qs, float* __restrict__ klrows){
  int m = blockIdx.x*4 + (threadIdx.x>>6);
  int s = threadIdx.x & 63;
  float pm   = pbuf[(long)m*128 + s];
  float praw = pbuf[(long)m*128 + 64 + s];
  float ps = fmaxf(praw,0.f) + log1pf(expf(-fabsf(praw))) + 1e-4f;
  float qmv = qm[(long)m*64+s], qsv = qs[(long)m*64+s];
  float d = qmv - pm;
  float kl = logf(ps/qsv) + (qsv*qsv + d*d)/(2.f*ps*ps) - 0.5f;
  #pragma unroll
  for (int off=32; off; off>>=1) kl += __shfl_xor(kl, off);
  if (s==0) klrows[m] = kl*(1.f/64.f);
}

__global__ void kl_reduce(const float* __restrict__ klrows, float* __restrict__ out){
  __shared__ float sm[256];
  float a = 0.f;
  for (int i=threadIdx.x; i<BT; i+=256) a += klrows[i];
  sm[threadIdx.x]=a; __syncthreads();
  for (int off=128; off; off>>=1){ if ((int)threadIdx.x<off) sm[threadIdx.x]+=sm[threadIdx.x+off]; __syncthreads(); }
  if (threadIdx.x==0) out[0] = sm[0] / (float)BT;
}

// ---------- reward/done heads (wave per row) ----------
__global__ void rewdone_kernel(const u16* __restrict__ det, const u16* __restrict__ sto,
    const float* __restrict__ Wr, const float* __restrict__ br,
    const float* __restrict__ Wd, const float* __restrict__ bd,
    float* __restrict__ orew, float* __restrict__ odone){
  int m = blockIdx.x*4 + (threadIdx.x>>6);
  int lane = threadIdx.x & 63;
  float ar=0.f, ad=0.f;
  for (int k=lane; k<HD+SD; k+=64){
    float f = (k<HD) ? bf2f(det[(long)m*HD+k]) : bf2f(sto[(long)m*SD + (k-HD)]);
    ar = fmaf(f, Wr[k], ar); ad = fmaf(f, Wd[k], ad);
  }
  #pragma unroll
  for (int off=32; off; off>>=1){ ar += __shfl_xor(ar, off); ad += __shfl_xor(ad, off); }
  if (lane==0){ orew[m]=ar+br[0]; odone[m]=ad+bd[0]; }
}

static char* carve(char*& base, size_t bytes){
  char* p = base; base += (bytes + 255) & ~(size_t)255; return p;
}

extern "C" void kernel_launch(void* const* d_in, const int* in_sizes, int n_in,
                              void* d_out, int out_size, void* d_ws, size_t ws_size,
                              hipStream_t stream) {
  const float* obs    = (const float*)d_in[0];
  const float* action = (const float*)d_in[1];
  const float* eps    = (const float*)d_in[2];
  const float* W_enc  = (const float*)d_in[3];
  const float* b_enc  = (const float*)d_in[4];
  const float* W_ih   = (const float*)d_in[5];
  const float* W_hh   = (const float*)d_in[6];
  const float* b_ih   = (const float*)d_in[7];
  const float* b_hh   = (const float*)d_in[8];
  const float* W_prior= (const float*)d_in[9];
  const float* b_prior= (const float*)d_in[10];
  const float* W_post = (const float*)d_in[11];
  const float* b_post = (const float*)d_in[12];
  const float* W_dec1 = (const float*)d_in[13];
  const float* b_dec1 = (const float*)d_in[14];
  const float* W_dec2 = (const float*)d_in[15];
  const float* b_dec2 = (const float*)d_in[16];
  const float* W_rew  = (const float*)d_in[17];
  const float* b_rew  = (const float*)d_in[18];
  const float* W_done = (const float*)d_in[19];
  const float* b_done = (const float*)d_in[20];

  char* w = (char*)d_ws;
  u16* obs_bf  = (u16*)carve(w, (size_t)BT*OBSD*2);   // later reused as hid_bf
  u16* emb_bf  = (u16*)carve(w, (size_t)BT*HD*2);
  u16* det_bf  = (u16*)carve(w, (size_t)BT*HD*2);
  u16* sto_bf  = (u16*)carve(w, (size_t)BT*SD*2);
  u16* act_bf  = (u16*)carve(w, (size_t)BT*ACTD*2);
  u16* Wenc_bf = (u16*)carve(w, (size_t)HD*OBSD*2);
  u16* Wih_bf  = (u16*)carve(w, (size_t)G3*(SD+ACTD)*2);
  u16* Whh_bf  = (u16*)carve(w, (size_t)G3*HD*2);
  u16* Wpri_bf = (u16*)carve(w, (size_t)2*SD*HD*2);
  u16* Wpos_bf = (u16*)carve(w, (size_t)2*SD*2*HD*2);
  u16* Wd1_bf  = (u16*)carve(w, (size_t)HD*(HD+SD)*2);
  u16* Wd2_bf  = (u16*)carve(w, (size_t)OBSD*HD*2);
  u16* zero_bf = (u16*)carve(w, 4096);
  float* deterF = (float*)carve(w, (size_t)BB*HD*4);
  float* qemb   = (float*)carve(w, (size_t)BT*128*4);
  float* qm_all = (float*)carve(w, (size_t)BT*SD*4);
  float* qs_all = (float*)carve(w, (size_t)BT*SD*4);
  float* p_buf  = (float*)carve(w, (size_t)BT*2*SD*4);
  float* klrows = (float*)carve(w, (size_t)BT*4);
  u16* hid_bf = obs_bf;   // union: obs_bf dead after encoder

  if ((size_t)(w - (char*)d_ws) > ws_size){
    hipMemsetAsync(d_out, 0xFF, 4, stream);
    return;
  }

  auto cvt = [&](const float* in, u16* out, long n){
    cvt_kernel<<<dim3(2048), dim3(256), 0, stream>>>(in, out, n);
  };
  cvt(obs, obs_bf, (long)BT*OBSD);
  cvt(action, act_bf, (long)BT*ACTD);
  cvt(W_enc, Wenc_bf, (long)HD*OBSD);
  cvt(W_ih, Wih_bf, (long)G3*(SD+ACTD));
  cvt(W_hh, Whh_bf, (long)G3*HD);
  cvt(W_prior, Wpri_bf, (long)2*SD*HD);
  cvt(W_post, Wpos_bf, (long)2*SD*2*HD);
  cvt(W_dec1, Wd1_bf, (long)HD*(HD+SD));
  cvt(W_dec2, Wd2_bf, (long)OBSD*HD);
  hipMemsetAsync(zero_bf, 0, 4096, stream);
  hipMemsetAsync(deterF, 0, (size_t)BB*HD*4, stream);

  // ---- Phase 1a: encoder  emb = relu(obs @ W_enc^T + b_enc)
  {
    GemmP q{};
    q.a0 = obs_bf;  q.lda0 = OBSD;
    q.b0 = Wenc_bf; q.ldb0 = OBSD;
    q.kc0=q.kc1=q.kc2=32; q.kcPerZ=32;
    q.cb = emb_bf; q.ldcb = HD;
    q.bias0 = b_enc; q.relu = 1;
    gemm_bf16<128,128><<<dim3(HD/128, BT/128, 1), 256, 0, stream>>>(q);
  }
  // ---- Phase 1b: Qemb = emb @ W_post[:,1024:]^T + b_post  (scan-independent half)
  {
    GemmP q{};
    q.a0 = emb_bf;       q.lda0 = HD;
    q.b0 = Wpos_bf + HD; q.ldb0 = 2*HD;
    q.kc0=q.kc1=q.kc2=32; q.kcPerZ=32;
    q.cf = qemb; q.ldc = 128;
    q.bias0 = b_post;
    gemm_bf16<64,64><<<dim3(128/64, BT/64, 1), 256, 0, stream>>>(q);
  }

  // ---- Phase 2: sequential scan, 2 launches per step ----
  for (int t=0; t<TT; ++t){
    const u16* sto_p = (t==0) ? zero_bf : (sto_bf + (long)(t-1)*SD);
    long ssto        = (t==0) ? 0 : (long)TT*SD;
    const u16* det_p = (t==0) ? zero_bf : (det_bf + (long)(t-1)*HD);
    long sdet        = (t==0) ? 0 : (long)TT*HD;
    gru_step<<<dim3(512), 256, 0, stream>>>(sto_p, ssto, act_bf + (long)t*ACTD,
        det_p, sdet, Wih_bf, Whh_bf, b_ih, b_hh, deterF, det_bf + (long)t*HD);
    post_step<<<dim3(32), 256, 0, stream>>>(det_bf + (long)t*HD, Wpos_bf,
        qemb + (long)t*128, eps + (long)t*SD,
        qm_all + (long)t*SD, qs_all + (long)t*SD, sto_bf + (long)t*SD);
  }

  // ---- Phase 3: batched heads ----
  {
    GemmP q{};
    q.a0 = det_bf;  q.lda0 = HD;
    q.b0 = Wpri_bf; q.ldb0 = HD;
    q.kc0=q.kc1=q.kc2=32; q.kcPerZ=32;
    q.cf = p_buf; q.ldc = 2*SD;
    q.bias0 = b_prior;
    gemm_bf16<64,64><<<dim3(2*SD/64, BT/64, 1), 256, 0, stream>>>(q);
  }
  kl_kernel<<<dim3(BT/4), 256, 0, stream>>>(p_buf, qm_all, qs_all, klrows);
  {
    GemmP q{};
    q.a0 = det_bf; q.lda0 = HD;
    q.a1 = sto_bf; q.lda1 = SD;
    q.b0 = Wd1_bf;      q.ldb0 = HD+SD;
    q.b1 = Wd1_bf + HD; q.ldb1 = HD+SD;
    q.kc0=32; q.kc1=34; q.kc2=34; q.kcPerZ=34;
    q.cb = hid_bf; q.ldcb = HD;
    q.bias0 = b_dec1; q.relu = 1;
    gemm_bf16<128,128><<<dim3(HD/128, BT/128, 1), 256, 0, stream>>>(q);
  }
  {
    GemmP q{};
    q.a0 = hid_bf; q.lda0 = HD;
    q.b0 = Wd2_bf; q.ldb0 = HD;
    q.kc0=q.kc1=q.kc2=32; q.kcPerZ=32;
    q.cf = (float*)d_out; q.ldc = OBSD;
    q.bias0 = b_dec2;
    gemm_bf16<128,128><<<dim3(OBSD/128, BT/128, 1), 256, 0, stream>>>(q);
  }
  rewdone_kernel<<<dim3(BT/4), 256, 0, stream>>>(det_bf, sto_bf, W_rew, b_rew, W_done, b_done,
      (float*)d_out + (long)BT*OBSD, (float*)d_out + (long)BT*OBSD + BT);
  kl_reduce<<<dim3(1), 256, 0, stream>>>(klrows, (float*)d_out + (long)BT*OBSD + 2*BT);
}